// Round 7
// baseline (2565.570 us; speedup 1.0000x reference)
//
#include <hip/hip_runtime.h>
#include <math.h>

// CapsuleLayer dynamic routing, MI355X fp32. Round 7.
// Lessons enforced: hard ~128-VGPR envelope (R5/R6 spills); W is thread-private
// -> no LDS for W; R4's serial load->use per il was the latency bottleneck.
// This round: block=512, thread owns (j, 2 d) = 8 float4 W (32 VGPR) =>
//   - x staged ONCE per block (8 KB LDS); PHASE0 loop is barrier-free
//   - single-buffer W prefetch (loads for il+1 issued after h consumes w[])
//   - 16 waves/CU occupancy (2 x 8-wave blocks)
// B=64, In=2048, Din=16, Nc=32, Dc=32, ROUTINGS=3.
// b starts at 0 => logits_t = hat . (v0+..+v_{t-1}); never store b or hat.

#define B_TOT   64
#define IN_CAPS 2048
#define DIN     16
#define NC      32
#define DC      32
#define JD      (NC * DC)                  // 1024
#define B_CHUNK 8
#define I_CHUNK 16
#define N_IG    (IN_CAPS / I_CHUNK)        // 128
#define EPS_SQ  1e-7f
#define SLOT_ELEMS ((size_t)B_TOT * JD)    // 65536 floats = 256 KB

__device__ __forceinline__ float dot4(float4 a, float4 b) {
    return a.x * b.x + a.y * b.y + a.z * b.z + a.w * b.w;
}

// 1-D grid 1024 blocks; decode bg=(bid>>3)&7, ig=(bid&7)|((bid>>6)<<3):
// the 8 bg-blocks of an ig are bids {c..c+56 step 8} -> co-resident, same XCD.
// block 512: t = j*16 + dp; j in [0,32), dp in [0,16), d0 = 2*dp.
// Thread's W slice per il: 32 contiguous floats (8 float4) -> 32 VGPR.
template <int PHASE>
__launch_bounds__(512, 4)
__global__ void caps_fused(const float* __restrict__ x,
                           const float* __restrict__ W,
                           const float* __restrict__ vsum,
                           float* __restrict__ P,
                           int slot_mask)
{
    __shared__ float xs[B_CHUNK][I_CHUNK * DIN];  // 8 KB: [b][il*16+k]
    __shared__ float ls[B_CHUNK][NC];             // 1 KB: logits, then c

    const int t  = threadIdx.x;          // 0..511
    const int j  = t >> 4;               // 0..31
    const int dp = t & 15;               // 0..15
    const int d0 = dp * 2;

    const int bid = blockIdx.x;          // 0..1023
    const int bg  = (bid >> 3) & 7;
    const int ig  = (bid & 7) | ((bid >> 6) << 3);
    const int b0  = bg * B_CHUNK;
    const int i0  = ig * I_CHUNK;

    // ---- stage x tile once: 2048 floats, fully coalesced ----
#pragma unroll
    for (int r = 0; r < 4; ++r) {
        const int idx = r * 512 + t;          // 0..2047
        const int bb  = idx >> 8;             // 0..7
        const int rem = idx & 255;            // il*16 + k
        xs[bb][rem] = x[(((size_t)(b0 + bb) * IN_CAPS + i0) * DIN) + rem];
    }

    // ---- vsum slice (PHASE1): constant across il, 2 floats per (b) ----
    float vv[B_CHUNK][2];
    if (PHASE == 1) {
#pragma unroll
        for (int b = 0; b < B_CHUNK; ++b) {
            const float2 v2 =
                *(const float2*)&vsum[((size_t)(b0 + b) * NC + j) * DC + d0];
            vv[b][0] = v2.x; vv[b][1] = v2.y;
        }
    }

    float acc[B_CHUNK][2];
#pragma unroll
    for (int b = 0; b < B_CHUNK; ++b) { acc[b][0] = 0.f; acc[b][1] = 0.f; }

    // ---- W prologue load (il=0): 8 float4 = 32 VGPR ----
    const float4* wp =
        (const float4*)(W + (((size_t)j * IN_CAPS + i0) * DC + d0) * DIN);
    float4 w[8];
#pragma unroll
    for (int q = 0; q < 8; ++q) w[q] = wp[q];

    __syncthreads();   // xs ready (covers PHASE0's only barrier need)

#pragma unroll 1
    for (int il = 0; il < I_CHUNK; ++il) {
        // hat for this thread's (j, d0, d0+1), all 8 batches
        float h[B_CHUNK][2];
#pragma unroll
        for (int b = 0; b < B_CHUNK; ++b) {
            const float* xb = &xs[b][il * DIN];
            const float4 x0 = *(const float4*)(xb + 0);    // LDS broadcast
            const float4 x1 = *(const float4*)(xb + 4);
            const float4 x2 = *(const float4*)(xb + 8);
            const float4 x3 = *(const float4*)(xb + 12);
            h[b][0] = dot4(w[0], x0) + dot4(w[1], x1)
                    + dot4(w[2], x2) + dot4(w[3], x3);
            h[b][1] = dot4(w[4], x0) + dot4(w[5], x1)
                    + dot4(w[6], x2) + dot4(w[7], x3);
        }

        // prefetch il+1's W into the (now-dead) w[] registers
        wp += DC * DIN / 4;                    // +128 float4
        if (il + 1 < I_CHUNK) {
#pragma unroll
            for (int q = 0; q < 8; ++q) w[q] = wp[q];
        }

        if (PHASE == 0) {
#pragma unroll
            for (int b = 0; b < B_CHUNK; ++b) {
                acc[b][0] += h[b][0];
                acc[b][1] += h[b][1];
            }
        } else {
            // logits: reduce h.vv over the 16 dp lanes (in-wave, width 16)
#pragma unroll
            for (int b = 0; b < B_CHUNK; ++b) {
                float lp = h[b][0] * vv[b][0] + h[b][1] * vv[b][1];
                lp += __shfl_xor(lp, 1, 16);
                lp += __shfl_xor(lp, 2, 16);
                lp += __shfl_xor(lp, 4, 16);
                lp += __shfl_xor(lp, 8, 16);
                if (dp == 0) ls[b][j] = lp;
            }
            __syncthreads();

            // softmax over j: threads 0..255 -> (bb = t>>5, jj = t&31)
            if (t < 256) {
                const int bb = t >> 5;
                const int jj = t & 31;
                const float l = ls[bb][jj];
                float m = l;
                m = fmaxf(m, __shfl_xor(m, 1, 32));
                m = fmaxf(m, __shfl_xor(m, 2, 32));
                m = fmaxf(m, __shfl_xor(m, 4, 32));
                m = fmaxf(m, __shfl_xor(m, 8, 32));
                m = fmaxf(m, __shfl_xor(m, 16, 32));
                const float e = __expf(l - m);
                float ssum = e;
                ssum += __shfl_xor(ssum, 1, 32);
                ssum += __shfl_xor(ssum, 2, 32);
                ssum += __shfl_xor(ssum, 4, 32);
                ssum += __shfl_xor(ssum, 8, 32);
                ssum += __shfl_xor(ssum, 16, 32);
                ls[bb][jj] = e / ssum;
            }
            __syncthreads();

            // c-weighted accumulate (h still live in registers)
#pragma unroll
            for (int b = 0; b < B_CHUNK; ++b) {
                const float c = ls[b][j];      // broadcast read
                acc[b][0] += c * h[b][0];
                acc[b][1] += c * h[b][1];
            }
        }
    }

    const float scale = (PHASE == 0) ? (1.f / NC) : 1.f;
    const int slot = ig & slot_mask;           // XCD-local partial buffer
    float* dst = P + (size_t)slot * SLOT_ELEMS + (size_t)b0 * JD + j * DC + d0;
#pragma unroll
    for (int b = 0; b < B_CHUNK; ++b) {
        atomicAdd(dst + (size_t)b * JD + 0, acc[b][0] * scale);
        atomicAdd(dst + (size_t)b * JD + 1, acc[b][1] * scale);
    }
}

// Sum nparts slots, squash over Dc=32 (32 consecutive lanes = one capsule),
// mode 0: VSUM = v ; 1: VSUM += v ; 2: OUT = v.  zero_after: re-zero P slots.
__global__ void reduce_squash(float* __restrict__ P, int nparts,
                              float* __restrict__ VSUM,
                              float* __restrict__ OUT, int mode, int zero_after)
{
    const int idx = blockIdx.x * blockDim.x + threadIdx.x;  // b*1024 + jd
    float val = 0.f;
    for (int s = 0; s < nparts; ++s)
        val += P[(size_t)s * SLOT_ELEMS + idx];
    if (zero_after) {
        for (int s = 0; s < nparts; ++s)
            P[(size_t)s * SLOT_ELEMS + idx] = 0.f;
    }

    float s2 = val * val;
#pragma unroll
    for (int off = 16; off >= 1; off >>= 1)
        s2 += __shfl_xor(s2, off, 32);
    const float sc = s2 / (1.f + s2) * rsqrtf(s2 + EPS_SQ);
    const float v  = sc * val;
    if (mode == 0)      VSUM[idx] = v;
    else if (mode == 1) VSUM[idx] += v;
    else                OUT[idx] = v;
}

extern "C" void kernel_launch(void* const* d_in, const int* in_sizes, int n_in,
                              void* d_out, int out_size, void* d_ws, size_t ws_size,
                              hipStream_t stream)
{
    const float* x = (const float*)d_in[0];   // [64, 2048, 16]
    const float* W = (const float*)d_in[1];   // [32, 2048, 32, 16]
    float* out = (float*)d_out;               // [64, 32, 32]

    // n_slots (pow2, <=8) from workspace: P = n_slots*256KB, then VSUM 256KB
    const size_t ws_floats = ws_size / sizeof(float);
    size_t avail = (ws_floats > SLOT_ELEMS) ? ws_floats - SLOT_ELEMS : 0;
    int n_slots = 1;
    while (n_slots < 8 && (size_t)(n_slots * 2) * SLOT_ELEMS <= avail)
        n_slots *= 2;
    const int slot_mask = n_slots - 1;

    float* P    = (float*)d_ws;
    float* VSUM = P + (size_t)n_slots * SLOT_ELEMS;

    const dim3 grid(N_IG * (B_TOT / B_CHUNK));  // 1024 blocks
    const dim3 blk(512);
    const int  rs_grid = (B_TOT * JD) / 256;    // 256

    hipMemsetAsync(P, 0, (size_t)n_slots * SLOT_ELEMS * sizeof(float), stream);

    // iter 0: uniform c = 1/32
    caps_fused<0><<<grid, blk, 0, stream>>>(x, W, nullptr, P, slot_mask);
    reduce_squash<<<rs_grid, 256, 0, stream>>>(P, n_slots, VSUM, out, 0, 1);

    // iter 1: logits = hat . v0
    caps_fused<1><<<grid, blk, 0, stream>>>(x, W, VSUM, P, slot_mask);
    reduce_squash<<<rs_grid, 256, 0, stream>>>(P, n_slots, VSUM, out, 1, 1);

    // iter 2: logits = hat . (v0+v1)
    caps_fused<1><<<grid, blk, 0, stream>>>(x, W, VSUM, P, slot_mask);
    reduce_squash<<<rs_grid, 256, 0, stream>>>(P, n_slots, VSUM, out, 2, 0);
}